// Round 14
// baseline (128.032 us; speedup 1.0000x reference)
//
#include <hip/hip_runtime.h>
#include <hip/hip_bf16.h>

typedef __attribute__((ext_vector_type(8))) short short8_t;
typedef __attribute__((ext_vector_type(4))) short s4v;
typedef __attribute__((ext_vector_type(4))) float f32x4_t;
typedef __attribute__((ext_vector_type(4))) unsigned u32x4_t;
using u16 = unsigned short;

constexpr int S_LEN = 2048;
constexpr int EMB   = 1024;
constexpr int NH    = 16;
constexpr int HD    = 64;
constexpr int BATCH = 2;
constexpr int MR    = BATCH * S_LEN;  // 4096
constexpr int E3    = 3 * EMB;        // 3072

#define L2E 1.44269504f

__device__ __forceinline__ u16 f2bf(float f) {
  unsigned u = __builtin_bit_cast(unsigned, f);
  unsigned r = 0x7fffu + ((u >> 16) & 1u);
  return (u16)((u + r) >> 16);
}

// packed f32x2 -> bf16x2 via intrinsic (RNE, compiler emits v_cvt_pk_bf16_f32)
__device__ __forceinline__ unsigned pkbf(float a, float b) {
  __hip_bfloat162 h = __float22bfloat162_rn(make_float2(a, b));
  unsigned u;
  __builtin_memcpy(&u, &h, 4);
  return u;
}

__device__ __forceinline__ void gld16(const void* g, void* l) {
  __builtin_amdgcn_global_load_lds(
      (const __attribute__((address_space(1))) void*)g,
      (__attribute__((address_space(3))) void*)l, 16, 0, 0);
}

// hardware transpose read. Canonical per-lane address = base + 8B*lane:
// lane l, elem j <- lds_elem[64*(l>>4) + 16*j + (l&15)] (+ offset/2 elems).
template <int OFF>
__device__ __forceinline__ s4v tr16(const __attribute__((address_space(3))) u16* p) {
  s4v d;
  asm volatile("ds_read_b64_tr_b16 %0, %1 offset:%2"
               : "=v"(d) : "v"(p), "n"(OFF));
  return d;
}

// ---------------- fused fp32 -> bf16 conversion ----------------------------
// dest layout (contiguous in ws): xb(4M) | Wq(1M,*0.125) | Wk | Wv | Wo
__global__ void k_cvt_all(const float* __restrict__ x, const float* __restrict__ Wq,
                          const float* __restrict__ Wk, const float* __restrict__ Wv,
                          const float* __restrict__ Wo, u16* __restrict__ out) {
  int i = blockIdx.x * 256 + threadIdx.x;  // float4 index, total 2M
  const float* src;
  int j;
  float sc = 1.0f;
  if (i < (1 << 20)) {
    src = x; j = i;
  } else {
    int jj = i - (1 << 20);
    int r = jj >> 18;
    j = jj & ((1 << 18) - 1);
    src = (r == 0) ? Wq : (r == 1) ? Wk : (r == 2) ? Wv : Wo;
    if (r == 0) sc = 0.125f;  // fold softmax 1/sqrt(64)
  }
  float4 v = reinterpret_cast<const float4*>(src)[j];
  ushort4 o;
  o.x = f2bf(v.x * sc); o.y = f2bf(v.y * sc);
  o.z = f2bf(v.z * sc); o.w = f2bf(v.w * sc);
  reinterpret_cast<ushort4*>(out)[i] = o;
}

// ---------------- bf16 GEMM 256x256, BK=64, 8 waves, 4-phase pipeline ------
// C = A @ B^T, bf16 out. Layouts/swizzle/epilogue identical to the
// r12-verified kernel; only the schedule changed: per K-tile, 4 phases
// {barrier; issue 2 stage-units of tile t+1; [ph0: vmcnt(2)]; ds_read
// phase subtile; 16 MFMA}. Unit order uB01|uB23|uA0,2|uA1,3 makes
// vmcnt(2) at ph0 prove all of tile t landed (t+1's 2 newest in flight).
__global__ __launch_bounds__(512, 1) void k_gemm256(
    const u16* __restrict__ A, const u16* __restrict__ Bw,
    u16* __restrict__ C, int M, int N) {
  constexpr int K = 1024;
  __shared__ u16 Ab[2][16384];   // [256][64] chunk-XOR swizzled
  __shared__ u16 Bb[2][16384];

  const int t    = threadIdx.x;
  const int ww   = t >> 6;         // wave 0..7
  const int ln15 = t & 15;
  const int lg   = (t >> 4) & 3;
  const int wr   = ww >> 2;        // 0..1 (M half)
  const int wc   = ww & 3;         // 0..3 (N quarter)

  // XCD-aware remap: nwg = 12*16 = 192, %8==0 -> bijective
  const int nwgx = gridDim.x;
  const int lin  = blockIdx.y * nwgx + blockIdx.x;
  const int cpx  = (nwgx * gridDim.y) >> 3;
  const int lin2 = (lin & 7) * cpx + (lin >> 3);
  const int m0   = (lin2 / nwgx) * 256;
  const int n0   = (lin2 % nwgx) * 256;

  // staging: unit i = tile rows 64i..64i+63 of one matrix; thread t stages
  // row srow, logical chunk (t&7)^(srow&7) (pre-swizzled source col).
  const int srow = t >> 3;                       // 0..63
  const int rlo  = (t >> 3) & 7;
  const int scol = 8 * ((t & 7) ^ rlo);          // source col elems

  // read offsets: logical chunk (4*kh+lg) of row r at position ^(r&7)
  const int kx  = 8 * (ln15 & 7);
  const int kc0 = (8 * lg) ^ kx;        // kh=0
  const int kc1 = (32 + 8 * lg) ^ kx;   // kh=1

  f32x4_t acc[8][4] = {};

#define U_A(buf, ki, i)                                                        \
  gld16(A + (size_t)(m0 + 64 * (i) + srow) * K + 64 * (ki) + scol,             \
        &Ab[buf][(i) * 4096 + ww * 512])
#define U_B(buf, ki, i)                                                        \
  gld16(Bw + (size_t)(n0 + 64 * (i) + srow) * K + 64 * (ki) + scol,            \
        &Bb[buf][(i) * 4096 + ww * 512])

// af reads for phase q (mi = 2q, 2q+1), both kh
#define AF_READ(q)                                                             \
  af[0][0] = *reinterpret_cast<const short8_t*>(                               \
      &Ab[cur][(wr * 128 + 16 * (2 * (q)) + ln15) * 64 + kc0]);                \
  af[0][1] = *reinterpret_cast<const short8_t*>(                               \
      &Ab[cur][(wr * 128 + 16 * (2 * (q)) + ln15) * 64 + kc1]);                \
  af[1][0] = *reinterpret_cast<const short8_t*>(                               \
      &Ab[cur][(wr * 128 + 16 * (2 * (q) + 1) + ln15) * 64 + kc0]);            \
  af[1][1] = *reinterpret_cast<const short8_t*>(                               \
      &Ab[cur][(wr * 128 + 16 * (2 * (q) + 1) + ln15) * 64 + kc1])

#define MFMA16(q)                                                              \
  __builtin_amdgcn_s_setprio(1);                                               \
  _Pragma("unroll")                                                            \
  for (int m2 = 0; m2 < 2; ++m2)                                               \
    _Pragma("unroll")                                                          \
    for (int ni = 0; ni < 4; ++ni) {                                           \
      acc[2 * (q) + m2][ni] = __builtin_amdgcn_mfma_f32_16x16x32_bf16(         \
          af[m2][0], bf[ni][0], acc[2 * (q) + m2][ni], 0, 0, 0);               \
      acc[2 * (q) + m2][ni] = __builtin_amdgcn_mfma_f32_16x16x32_bf16(         \
          af[m2][1], bf[ni][1], acc[2 * (q) + m2][ni], 0, 0, 0);               \
    }                                                                          \
  __builtin_amdgcn_s_setprio(0)

  constexpr int nk = K / 64;   // 16
  // prologue: stage tile 0 completely (8 units)
  U_B(0, 0, 0); U_B(0, 0, 1); U_B(0, 0, 2); U_B(0, 0, 3);
  U_A(0, 0, 0); U_A(0, 0, 2); U_A(0, 0, 1); U_A(0, 0, 3);
  int cur = 0;

  for (int ki = 0; ki < nk; ++ki) {
    const bool nxt = (ki + 1 < nk);
    short8_t bf[4][2], af[2][2];

    // ---- phase 0 ----
    asm volatile("s_barrier" ::: "memory");
    if (nxt) {
      U_B(cur ^ 1, ki + 1, 0); U_B(cur ^ 1, ki + 1, 1);
      asm volatile("s_waitcnt vmcnt(2)" ::: "memory");  // tile ki all landed
    } else {
      asm volatile("s_waitcnt vmcnt(0)" ::: "memory");
    }
#pragma unroll
    for (int ni = 0; ni < 4; ++ni) {
      bf[ni][0] = *reinterpret_cast<const short8_t*>(
          &Bb[cur][(wc * 64 + 16 * ni + ln15) * 64 + kc0]);
      bf[ni][1] = *reinterpret_cast<const short8_t*>(
          &Bb[cur][(wc * 64 + 16 * ni + ln15) * 64 + kc1]);
    }
    AF_READ(0);
    MFMA16(0);

    // ---- phase 1 ----
    asm volatile("s_barrier" ::: "memory");
    if (nxt) { U_B(cur ^ 1, ki + 1, 2); U_B(cur ^ 1, ki + 1, 3); }
    AF_READ(1);
    MFMA16(1);

    // ---- phase 2 ----
    asm volatile("s_barrier" ::: "memory");
    if (nxt) { U_A(cur ^ 1, ki + 1, 0); U_A(cur ^ 1, ki + 1, 2); }
    AF_READ(2);
    MFMA16(2);

    // ---- phase 3 ----
    asm volatile("s_barrier" ::: "memory");
    if (nxt) { U_A(cur ^ 1, ki + 1, 1); U_A(cur ^ 1, ki + 1, 3); }
    AF_READ(3);
    MFMA16(3);

    cur ^= 1;
  }
#undef U_A
#undef U_B
#undef AF_READ
#undef MFMA16

  // epilogue (r12-verified): C[m0+wr*128+16mi+4lg+rr][n0+wc*64+16ni+ln15]
#pragma unroll
  for (int mi = 0; mi < 8; ++mi) {
#pragma unroll
    for (int ni = 0; ni < 4; ++ni) {
      const int col = n0 + wc * 64 + 16 * ni + ln15;
#pragma unroll
      for (int rr = 0; rr < 4; ++rr) {
        const int row = m0 + wr * 128 + 16 * mi + 4 * lg + rr;
        C[(size_t)row * N + col] = f2bf(acc[mi][ni][rr]);
      }
    }
  }
}

// ---------------- bf16 GEMM, B^T input, 128x128 tile (r9-verified) ---------
// 2-phase double-buffered staging + T1 XCD swizzle. Used for out-proj.
template <bool F32OUT>
__global__ __launch_bounds__(256) void k_gemm_bt(
    const u16* __restrict__ A, const u16* __restrict__ Bw,
    void* __restrict__ Cv, const float* __restrict__ bias,
    int M, int N, int K) {
  __shared__ short As[2][128 * 32];
  __shared__ short Bs[2][128 * 32];
  const int t    = threadIdx.x;
  const int w    = t >> 6;
  const int ln15 = t & 15;
  const int lg   = (t >> 4) & 3;
  const int wr   = w >> 1, wc = w & 1;

  const int nwgx = gridDim.x;
  const int lin  = blockIdx.y * nwgx + blockIdx.x;
  const int cpx  = (nwgx * gridDim.y) >> 3;
  const int lin2 = (lin & 7) * cpx + (lin >> 3);
  const int m0   = (lin2 / nwgx) * 128;
  const int n0   = (lin2 % nwgx) * 128;

  const int srow = t >> 2;
  const int scol = (t & 3) * 8;
  const u16* gA = A + (size_t)(m0 + srow) * K + scol;
  const u16* gB = Bw + (size_t)(n0 + srow) * K + scol;
  const int lofs = w * 512;

  f32x4_t acc[4][4] = {};

#define GSTAGE(buf, k0)                                                        \
  do {                                                                         \
    gld16(gA + (k0), &As[buf][lofs]);                                          \
    gld16(gA + (size_t)64 * K + (k0), &As[buf][lofs + 2048]);                  \
    gld16(gB + (k0), &Bs[buf][lofs]);                                          \
    gld16(gB + (size_t)64 * K + (k0), &Bs[buf][lofs + 2048]);                  \
  } while (0)

  const int nk = K >> 5;
  GSTAGE(0, 0);
  int cur = 0;

  for (int ki = 0; ki < nk; ++ki) {
    asm volatile("s_barrier" ::: "memory");
    if (ki + 1 < nk) {
      GSTAGE(cur ^ 1, (ki + 1) * 32);
      asm volatile("s_waitcnt vmcnt(4)" ::: "memory");
    } else {
      asm volatile("s_waitcnt vmcnt(0)" ::: "memory");
    }
    asm volatile("s_barrier" ::: "memory");

    short8_t af[4], bf[4];
#pragma unroll
    for (int i = 0; i < 4; ++i) {
      af[i] = *reinterpret_cast<const short8_t*>(
          &As[cur][(wr * 64 + i * 16 + ln15) * 32 + 8 * lg]);
      bf[i] = *reinterpret_cast<const short8_t*>(
          &Bs[cur][(wc * 64 + i * 16 + ln15) * 32 + 8 * lg]);
    }
#pragma unroll
    for (int i = 0; i < 4; ++i)
#pragma unroll
      for (int j = 0; j < 4; ++j)
        acc[i][j] = __builtin_amdgcn_mfma_f32_16x16x32_bf16(
            af[i], bf[j], acc[i][j], 0, 0, 0);
    cur ^= 1;
  }
#undef GSTAGE

  if (F32OUT) {
    float* C = reinterpret_cast<float*>(Cv);
#pragma unroll
    for (int i = 0; i < 4; ++i)
#pragma unroll
      for (int j = 0; j < 4; ++j) {
        const int col = n0 + wc * 64 + j * 16 + ln15;
        const float bv = bias ? bias[col] : 0.0f;
#pragma unroll
        for (int r = 0; r < 4; ++r) {
          const int row = m0 + wr * 64 + i * 16 + lg * 4 + r;
          C[(size_t)row * N + col] = acc[i][j][r] + bv;
        }
      }
  } else {
    u16* C = reinterpret_cast<u16*>(Cv);
#pragma unroll
    for (int i = 0; i < 4; ++i)
#pragma unroll
      for (int j = 0; j < 4; ++j) {
        const int col = n0 + wc * 64 + j * 16 + ln15;
#pragma unroll
        for (int r = 0; r < 4; ++r) {
          const int row = m0 + wr * 64 + i * 16 + lg * 4 + r;
          C[(size_t)row * N + col] = f2bf(acc[i][j][r]);
        }
      }
  }
}

// ---------------- causal flash attention, swapped-QK^T (r9-exact, frozen) ---
__global__ __launch_bounds__(256, 4) void k_attn2(const u16* __restrict__ QKV,
                                                  u16* __restrict__ ctx) {
  __shared__ u16 Ks[2][64 * 64];
  __shared__ u16 Vs[2][64 * 64];

  const int t    = threadIdx.x;
  const int w    = t >> 6;
  const int l    = t & 63;
  const int ln15 = t & 15;
  const int lg   = (l >> 4) & 3;

  const int qt = 31 - blockIdx.y;
  const int bh = blockIdx.x;
  const int b  = bh >> 4, h = bh & 15;

  const u16* KVb = QKV + (size_t)b * S_LEN * E3 + h * HD;
  const u16* Kg  = KVb + 1024;
  const u16* Vg  = KVb + 2048;
  const int qrow = qt * 64 + w * 16;

  short8_t qf[2];
  {
    const u16* qp = KVb + (size_t)(qrow + ln15) * E3 + 8 * lg;
    qf[0] = *reinterpret_cast<const short8_t*>(qp);
    qf[1] = *reinterpret_cast<const short8_t*>(qp + 32);
  }

  const int krow_lo = l >> 3;
  const int kcol    = 8 * ((l & 7) ^ krow_lo);
  const int vkv     = l >> 1;
  const int vcol    = 16 * w + 8 * (l & 1);

  const int kx  = 8 * (ln15 & 7);
  const int kc0 = (8 * lg) ^ kx;
  const int kc1 = (32 + 8 * lg) ^ kx;

#define STAGE(buf, kv0)                                                        \
  do {                                                                         \
    gld16(Kg + (size_t)((kv0) + 16 * w + krow_lo) * E3 + kcol,                 \
          &Ks[buf][1024 * w]);                                                 \
    gld16(Kg + (size_t)((kv0) + 16 * w + 8 + krow_lo) * E3 + kcol,             \
          &Ks[buf][1024 * w + 512]);                                           \
    gld16(Vg + (size_t)((kv0) + vkv) * E3 + vcol, &Vs[buf][1024 * w]);         \
    gld16(Vg + (size_t)((kv0) + 32 + vkv) * E3 + vcol,                         \
          &Vs[buf][1024 * w + 512]);                                           \
  } while (0)

  f32x4_t o[4] = {};
  float mrow = -3e38f, lrow = 0.0f;
  const int nt_tiles = qt + 1;

  STAGE(0, 0);
  int cur = 0;

  for (int kvt = 0; kvt < nt_tiles; ++kvt) {
    const int kv0 = kvt * 64;
    asm volatile("s_barrier" ::: "memory");
    if (kvt + 1 < nt_tiles) {
      STAGE(cur ^ 1, kv0 + 64);
      asm volatile("s_waitcnt vmcnt(4)" ::: "memory");
    } else {
      asm volatile("s_waitcnt vmcnt(0)" ::: "memory");
    }
    asm volatile("s_barrier" ::: "memory");

    const __attribute__((address_space(3))) u16* vp =
        (const __attribute__((address_space(3))) u16*)&Vs[cur][4 * l];
    s4v vf[4][2][2];
#pragma unroll
    for (int nt = 0; nt < 4; ++nt) {
      if (nt == 0) { vf[0][0][0]=tr16<0>(vp);    vf[0][0][1]=tr16<512>(vp);
                     vf[0][1][0]=tr16<1024>(vp); vf[0][1][1]=tr16<1536>(vp); }
      if (nt == 1) { vf[1][0][0]=tr16<2048>(vp); vf[1][0][1]=tr16<2560>(vp);
                     vf[1][1][0]=tr16<3072>(vp); vf[1][1][1]=tr16<3584>(vp); }
      if (nt == 2) { vf[2][0][0]=tr16<4096>(vp); vf[2][0][1]=tr16<4608>(vp);
                     vf[2][1][0]=tr16<5120>(vp); vf[2][1][1]=tr16<5632>(vp); }
      if (nt == 3) { vf[3][0][0]=tr16<6144>(vp); vf[3][0][1]=tr16<6656>(vp);
                     vf[3][1][0]=tr16<7168>(vp); vf[3][1][1]=tr16<7680>(vp); }
    }

    f32x4_t tacc[4];
    __builtin_amdgcn_s_setprio(1);
#pragma unroll
    for (int ks = 0; ks < 4; ++ks) {
      const int R = 16 * ks + ln15;
      short8_t kf0 = *reinterpret_cast<const short8_t*>(&Ks[cur][R * 64 + kc0]);
      short8_t kf1 = *reinterpret_cast<const short8_t*>(&Ks[cur][R * 64 + kc1]);
      f32x4_t a = {0.f, 0.f, 0.f, 0.f};
      a = __builtin_amdgcn_mfma_f32_16x16x32_bf16(kf0, qf[0], a, 0, 0, 0);
      a = __builtin_amdgcn_mfma_f32_16x16x32_bf16(kf1, qf[1], a, 0, 0, 0);
      tacc[ks] = a;
    }
    __builtin_amdgcn_s_setprio(0);

    if (kvt == qt) {
      const int qg = qrow + ln15;
#pragma unroll
      for (int ks = 0; ks < 4; ++ks)
#pragma unroll
        for (int r = 0; r < 4; ++r)
          if (kv0 + 16 * ks + 4 * lg + r > qg) tacc[ks][r] = -3e38f;
    }

    float rm = fmaxf(
        fmaxf(fmaxf(fmaxf(tacc[0][0], tacc[0][1]), fmaxf(tacc[0][2], tacc[0][3])),
              fmaxf(fmaxf(tacc[1][0], tacc[1][1]), fmaxf(tacc[1][2], tacc[1][3]))),
        fmaxf(fmaxf(fmaxf(tacc[2][0], tacc[2][1]), fmaxf(tacc[2][2], tacc[2][3])),
              fmaxf(fmaxf(tacc[3][0], tacc[3][1]), fmaxf(tacc[3][2], tacc[3][3]))));
    rm = fmaxf(rm, __shfl_xor(rm, 16, 64));
    rm = fmaxf(rm, __shfl_xor(rm, 32, 64));

    if (__any(rm > mrow)) {
      const float nm = fmaxf(mrow, rm);
      const float sc = exp2f((mrow - nm) * L2E);
      mrow = nm;
      lrow *= sc;
#pragma unroll
      for (int r = 0; r < 4; ++r) {
        const float so = __shfl(sc, 20 * lg + r, 64);
#pragma unroll
        for (int nt = 0; nt < 4; ++nt) o[nt][r] *= so;
      }
    }

    const float nmL = mrow * L2E;
    float p[4][4];
    float rs = 0.0f;
#pragma unroll
    for (int ks = 0; ks < 4; ++ks)
#pragma unroll
      for (int r = 0; r < 4; ++r) {
        const float pv = exp2f(fmaf(tacc[ks][r], L2E, -nmL));
        p[ks][r] = pv;
        rs += pv;
      }
    rs += __shfl_xor(rs, 16, 64);
    rs += __shfl_xor(rs, 32, 64);
    lrow += rs;

    short8_t pf[2];
#pragma unroll
    for (int s2 = 0; s2 < 2; ++s2) {
      u32x4_t pu;
      pu[0] = pkbf(p[2 * s2][0], p[2 * s2][1]);
      pu[1] = pkbf(p[2 * s2][2], p[2 * s2][3]);
      pu[2] = pkbf(p[2 * s2 + 1][0], p[2 * s2 + 1][1]);
      pu[3] = pkbf(p[2 * s2 + 1][2], p[2 * s2 + 1][3]);
      pf[s2] = __builtin_bit_cast(short8_t, pu);
    }

    asm volatile("s_waitcnt lgkmcnt(0)");
    __builtin_amdgcn_sched_barrier(0);

    __builtin_amdgcn_s_setprio(1);
#pragma unroll
    for (int nt = 0; nt < 4; ++nt) {
#pragma unroll
      for (int s2 = 0; s2 < 2; ++s2) {
        short8_t bv = __builtin_shufflevector(vf[nt][s2][0], vf[nt][s2][1],
                                              0, 1, 2, 3, 4, 5, 6, 7);
        o[nt] = __builtin_amdgcn_mfma_f32_16x16x32_bf16(pf[s2], bv, o[nt], 0, 0, 0);
      }
    }
    __builtin_amdgcn_s_setprio(0);
    cur ^= 1;
  }
#undef STAGE

  const float linv = 1.0f / lrow;
#pragma unroll
  for (int r = 0; r < 4; ++r) {
    const float li = __shfl(linv, 20 * lg + r, 64);
    u16* op = ctx + (size_t)(b * S_LEN + qrow + 4 * lg + r) * EMB + h * HD;
#pragma unroll
    for (int nt = 0; nt < 4; ++nt)
      op[nt * 16 + ln15] = f2bf(o[nt][r] * li);
  }
}

// ---------------------------------------------------------------------------
extern "C" void kernel_launch(void* const* d_in, const int* in_sizes, int n_in,
                              void* d_out, int out_size, void* d_ws, size_t ws_size,
                              hipStream_t stream) {
  const float* x  = (const float*)d_in[0];
  const float* Wq = (const float*)d_in[1];
  const float* Wk = (const float*)d_in[2];
  const float* Wv = (const float*)d_in[3];
  const float* Wo = (const float*)d_in[4];
  const float* bo = (const float*)d_in[5];

  u16* ws   = (u16*)d_ws;
  u16* xb   = ws;                               // 4096*1024
  u16* wcat = xb + (size_t)MR * EMB;            // 3*1024*1024 (Wq|Wk|Wv rows)
  u16* wob  = wcat + (size_t)3 * EMB * EMB;     // 1024*1024
  u16* qkv  = wob + (size_t)EMB * EMB;          // 4096*3072
  u16* ctxb = qkv + (size_t)MR * E3;            // 4096*1024

  // fused fp32 -> bf16 (x | Wq*0.125 | Wk | Wv | Wo), dest contiguous at xb
  k_cvt_all<<<8192, 256, 0, stream>>>(x, Wq, Wk, Wv, Wo, xb);

  // QKV = x @ Wcat^T  (M=4096, N=3072, K=1024), 256^2 4-phase pipeline
  k_gemm256<<<dim3(E3 / 256, MR / 256), 512, 0, stream>>>(
      xb, wcat, qkv, MR, E3);

  // causal flash attention -> ctx (bf16), r9-exact
  k_attn2<<<dim3(BATCH * NH, 32), 256, 0, stream>>>(qkv, ctxb);

  // out = ctx @ Wo^T + bo  (fp32 out)
  k_gemm_bt<true><<<dim3(EMB / 128, MR / 128), 256, 0, stream>>>(
      ctxb, wob, d_out, bo, MR, EMB, EMB);
}

// Round 15
// 117.512 us; speedup vs baseline: 1.0895x; 1.0895x over previous
//
#include <hip/hip_runtime.h>
#include <hip/hip_bf16.h>

typedef __attribute__((ext_vector_type(8))) short short8_t;
typedef __attribute__((ext_vector_type(4))) short s4v;
typedef __attribute__((ext_vector_type(4))) float f32x4_t;
typedef __attribute__((ext_vector_type(4))) unsigned u32x4_t;
using u16 = unsigned short;

constexpr int S_LEN = 2048;
constexpr int EMB   = 1024;
constexpr int NH    = 16;
constexpr int HD    = 64;
constexpr int BATCH = 2;
constexpr int MR    = BATCH * S_LEN;  // 4096
constexpr int E3    = 3 * EMB;        // 3072

#define L2E 1.44269504f

__device__ __forceinline__ u16 f2bf(float f) {
  unsigned u = __builtin_bit_cast(unsigned, f);
  unsigned r = 0x7fffu + ((u >> 16) & 1u);
  return (u16)((u + r) >> 16);
}

// packed f32x2 -> bf16x2 via intrinsic (RNE, compiler emits v_cvt_pk_bf16_f32)
__device__ __forceinline__ unsigned pkbf(float a, float b) {
  __hip_bfloat162 h = __float22bfloat162_rn(make_float2(a, b));
  unsigned u;
  __builtin_memcpy(&u, &h, 4);
  return u;
}

__device__ __forceinline__ void gld16(const void* g, void* l) {
  __builtin_amdgcn_global_load_lds(
      (const __attribute__((address_space(1))) void*)g,
      (__attribute__((address_space(3))) void*)l, 16, 0, 0);
}

// hardware transpose read. Canonical per-lane address = base + 8B*lane:
// lane l, elem j <- lds_elem[64*(l>>4) + 16*j + (l&15)] (+ offset/2 elems).
template <int OFF>
__device__ __forceinline__ s4v tr16(const __attribute__((address_space(3))) u16* p) {
  s4v d;
  asm volatile("ds_read_b64_tr_b16 %0, %1 offset:%2"
               : "=v"(d) : "v"(p), "n"(OFF));
  return d;
}

// ---------------- fused fp32 -> bf16 conversion ----------------------------
// dest layout (contiguous in ws): xb(4M) | Wq(1M,*0.125) | Wk | Wv | Wo
__global__ void k_cvt_all(const float* __restrict__ x, const float* __restrict__ Wq,
                          const float* __restrict__ Wk, const float* __restrict__ Wv,
                          const float* __restrict__ Wo, u16* __restrict__ out) {
  int i = blockIdx.x * 256 + threadIdx.x;  // float4 index, total 2M
  const float* src;
  int j;
  float sc = 1.0f;
  if (i < (1 << 20)) {
    src = x; j = i;
  } else {
    int jj = i - (1 << 20);
    int r = jj >> 18;
    j = jj & ((1 << 18) - 1);
    src = (r == 0) ? Wq : (r == 1) ? Wk : (r == 2) ? Wv : Wo;
    if (r == 0) sc = 0.125f;  // fold softmax 1/sqrt(64)
  }
  float4 v = reinterpret_cast<const float4*>(src)[j];
  ushort4 o;
  o.x = f2bf(v.x * sc); o.y = f2bf(v.y * sc);
  o.z = f2bf(v.z * sc); o.w = f2bf(v.w * sc);
  reinterpret_cast<ushort4*>(out)[i] = o;
}

// ---------------- bf16 GEMM, B^T input (C = A @ B^T), 128x128 tile ---------
// 2-phase double-buffered staging (r9-verified). T1 XCD swizzle.
template <bool F32OUT>
__global__ __launch_bounds__(256) void k_gemm_bt(
    const u16* __restrict__ A, const u16* __restrict__ Bw,
    void* __restrict__ Cv, const float* __restrict__ bias,
    int M, int N, int K) {
  __shared__ short As[2][128 * 32];
  __shared__ short Bs[2][128 * 32];
  const int t    = threadIdx.x;
  const int w    = t >> 6;
  const int ln15 = t & 15;
  const int lg   = (t >> 4) & 3;
  const int wr   = w >> 1, wc = w & 1;

  // XCD-aware block remap (nwg % 8 == 0 for all launches here)
  const int nwgx = gridDim.x;
  const int lin  = blockIdx.y * nwgx + blockIdx.x;
  const int cpx  = (nwgx * gridDim.y) >> 3;
  const int lin2 = (lin & 7) * cpx + (lin >> 3);
  const int m0   = (lin2 / nwgx) * 128;
  const int n0   = (lin2 % nwgx) * 128;

  const int srow = t >> 2;
  const int scol = (t & 3) * 8;
  const u16* gA = A + (size_t)(m0 + srow) * K + scol;
  const u16* gB = Bw + (size_t)(n0 + srow) * K + scol;
  const int lofs = w * 512;  // wave-uniform LDS base (lane adds 16B slot)

  f32x4_t acc[4][4] = {};

#define GSTAGE(buf, k0)                                                        \
  do {                                                                         \
    gld16(gA + (k0), &As[buf][lofs]);                                          \
    gld16(gA + (size_t)64 * K + (k0), &As[buf][lofs + 2048]);                  \
    gld16(gB + (k0), &Bs[buf][lofs]);                                          \
    gld16(gB + (size_t)64 * K + (k0), &Bs[buf][lofs + 2048]);                  \
  } while (0)

  const int nk = K >> 5;
  GSTAGE(0, 0);
  int cur = 0;

  for (int ki = 0; ki < nk; ++ki) {
    asm volatile("s_barrier" ::: "memory");  // all waves done reading buf^1
    if (ki + 1 < nk) {
      GSTAGE(cur ^ 1, (ki + 1) * 32);
      asm volatile("s_waitcnt vmcnt(4)" ::: "memory");  // tile ki landed
    } else {
      asm volatile("s_waitcnt vmcnt(0)" ::: "memory");
    }
    asm volatile("s_barrier" ::: "memory");  // buf[cur] ready for all waves

    short8_t af[4], bf[4];
#pragma unroll
    for (int i = 0; i < 4; ++i) {
      af[i] = *reinterpret_cast<const short8_t*>(
          &As[cur][(wr * 64 + i * 16 + ln15) * 32 + 8 * lg]);
      bf[i] = *reinterpret_cast<const short8_t*>(
          &Bs[cur][(wc * 64 + i * 16 + ln15) * 32 + 8 * lg]);
    }
#pragma unroll
    for (int i = 0; i < 4; ++i)
#pragma unroll
      for (int j = 0; j < 4; ++j)
        acc[i][j] = __builtin_amdgcn_mfma_f32_16x16x32_bf16(
            af[i], bf[j], acc[i][j], 0, 0, 0);
    cur ^= 1;
  }
#undef GSTAGE

  if (F32OUT) {
    float* C = reinterpret_cast<float*>(Cv);
#pragma unroll
    for (int i = 0; i < 4; ++i)
#pragma unroll
      for (int j = 0; j < 4; ++j) {
        const int col = n0 + wc * 64 + j * 16 + ln15;
        const float bv = bias ? bias[col] : 0.0f;
#pragma unroll
        for (int r = 0; r < 4; ++r) {
          const int row = m0 + wr * 64 + i * 16 + lg * 4 + r;
          C[(size_t)row * N + col] = acc[i][j][r] + bv;
        }
      }
  } else {
    u16* C = reinterpret_cast<u16*>(Cv);
#pragma unroll
    for (int i = 0; i < 4; ++i)
#pragma unroll
      for (int j = 0; j < 4; ++j) {
        const int col = n0 + wc * 64 + j * 16 + ln15;
#pragma unroll
        for (int r = 0; r < 4; ++r) {
          const int row = m0 + wr * 64 + i * 16 + lg * 4 + r;
          C[(size_t)row * N + col] = f2bf(acc[i][j][r]);
        }
      }
  }
}

// ---------------- causal flash attention, swapped-QK^T (r9-exact) -----------
// 4 waves/block, 16 q-rows/wave, KV tiles 64, double-buffered counted-vmcnt.
__global__ __launch_bounds__(256, 4) void k_attn2(const u16* __restrict__ QKV,
                                                  u16* __restrict__ ctx) {
  __shared__ u16 Ks[2][64 * 64];
  __shared__ u16 Vs[2][64 * 64];

  const int t    = threadIdx.x;
  const int w    = t >> 6;
  const int l    = t & 63;
  const int ln15 = t & 15;
  const int lg   = (l >> 4) & 3;

  // LPT: heaviest qt dispatched first
  const int qt = 31 - blockIdx.y;
  const int bh = blockIdx.x;
  const int b  = bh >> 4, h = bh & 15;

  const u16* KVb = QKV + (size_t)b * S_LEN * E3 + h * HD;
  const u16* Kg  = KVb + 1024;
  const u16* Vg  = KVb + 2048;
  const int qrow = qt * 64 + w * 16;

  // Q fragments (B-operand): lane (ln15,lg): Q[qrow+ln15][32*sd + 8*lg ..+7]
  short8_t qf[2];
  {
    const u16* qp = KVb + (size_t)(qrow + ln15) * E3 + 8 * lg;
    qf[0] = *reinterpret_cast<const short8_t*>(qp);
    qf[1] = *reinterpret_cast<const short8_t*>(qp + 32);
  }

  // staging address components
  const int krow_lo = l >> 3;                    // row&7 of K stage row
  const int kcol    = 8 * ((l & 7) ^ krow_lo);   // pre-swizzled source col
  const int vkv     = l >> 1;                    // 0..31
  const int vcol    = 16 * w + 8 * (l & 1);      // dc=w chunk

  // K-frag read offsets (swizzled): chunk XOR with ln15&7
  const int kx  = 8 * (ln15 & 7);
  const int kc0 = (8 * lg) ^ kx;         // sd=0
  const int kc1 = (32 + 8 * lg) ^ kx;    // sd=1

#define STAGE(buf, kv0)                                                        \
  do {                                                                         \
    gld16(Kg + (size_t)((kv0) + 16 * w + krow_lo) * E3 + kcol,                 \
          &Ks[buf][1024 * w]);                                                 \
    gld16(Kg + (size_t)((kv0) + 16 * w + 8 + krow_lo) * E3 + kcol,             \
          &Ks[buf][1024 * w + 512]);                                           \
    gld16(Vg + (size_t)((kv0) + vkv) * E3 + vcol, &Vs[buf][1024 * w]);         \
    gld16(Vg + (size_t)((kv0) + 32 + vkv) * E3 + vcol,                         \
          &Vs[buf][1024 * w + 512]);                                           \
  } while (0)

  f32x4_t o[4] = {};
  float mrow = -3e38f, lrow = 0.0f;
  const int nt_tiles = qt + 1;

  STAGE(0, 0);
  int cur = 0;

  for (int kvt = 0; kvt < nt_tiles; ++kvt) {
    const int kv0 = kvt * 64;
    asm volatile("s_barrier" ::: "memory");  // all waves done reading buf[cur^1]
    if (kvt + 1 < nt_tiles) {
      STAGE(cur ^ 1, kv0 + 64);
      asm volatile("s_waitcnt vmcnt(4)" ::: "memory");
    } else {
      asm volatile("s_waitcnt vmcnt(0)" ::: "memory");
    }
    asm volatile("s_barrier" ::: "memory");  // buf[cur] ready for all waves

    // ---- issue V tr-reads early (latency hides under QK^T + softmax) ----
    // elem j of half h = V[kv0 + 32*s2 + 16*h + 4*lg + j][16*nt + ln15].
    const __attribute__((address_space(3))) u16* vp =
        (const __attribute__((address_space(3))) u16*)&Vs[cur][4 * l];
    s4v vf[4][2][2];
#pragma unroll
    for (int nt = 0; nt < 4; ++nt) {
      // OFF bytes = 2048*nt + 1024*s2 + 512*h
      if (nt == 0) { vf[0][0][0]=tr16<0>(vp);    vf[0][0][1]=tr16<512>(vp);
                     vf[0][1][0]=tr16<1024>(vp); vf[0][1][1]=tr16<1536>(vp); }
      if (nt == 1) { vf[1][0][0]=tr16<2048>(vp); vf[1][0][1]=tr16<2560>(vp);
                     vf[1][1][0]=tr16<3072>(vp); vf[1][1][1]=tr16<3584>(vp); }
      if (nt == 2) { vf[2][0][0]=tr16<4096>(vp); vf[2][0][1]=tr16<4608>(vp);
                     vf[2][1][0]=tr16<5120>(vp); vf[2][1][1]=tr16<5632>(vp); }
      if (nt == 3) { vf[3][0][0]=tr16<6144>(vp); vf[3][0][1]=tr16<6656>(vp);
                     vf[3][1][0]=tr16<7168>(vp); vf[3][1][1]=tr16<7680>(vp); }
    }

    // ---- S^T = mfma(K, Q): lane holds S[q=qrow+ln15][kv=kv0+16ks+4lg+r] ----
    f32x4_t tacc[4];
    __builtin_amdgcn_s_setprio(1);
#pragma unroll
    for (int ks = 0; ks < 4; ++ks) {
      const int R = 16 * ks + ln15;
      short8_t kf0 = *reinterpret_cast<const short8_t*>(&Ks[cur][R * 64 + kc0]);
      short8_t kf1 = *reinterpret_cast<const short8_t*>(&Ks[cur][R * 64 + kc1]);
      f32x4_t a = {0.f, 0.f, 0.f, 0.f};
      a = __builtin_amdgcn_mfma_f32_16x16x32_bf16(kf0, qf[0], a, 0, 0, 0);
      a = __builtin_amdgcn_mfma_f32_16x16x32_bf16(kf1, qf[1], a, 0, 0, 0);
      tacc[ks] = a;
    }
    __builtin_amdgcn_s_setprio(0);

    // ---- causal mask (diagonal tile only) ----
    if (kvt == qt) {
      const int qg = qrow + ln15;
#pragma unroll
      for (int ks = 0; ks < 4; ++ks)
#pragma unroll
        for (int r = 0; r < 4; ++r)
          if (kv0 + 16 * ks + 4 * lg + r > qg) tacc[ks][r] = -3e38f;
    }

    // ---- online softmax: lane owns 16 of row q=ln15's values ----
    float rm = fmaxf(
        fmaxf(fmaxf(fmaxf(tacc[0][0], tacc[0][1]), fmaxf(tacc[0][2], tacc[0][3])),
              fmaxf(fmaxf(tacc[1][0], tacc[1][1]), fmaxf(tacc[1][2], tacc[1][3]))),
        fmaxf(fmaxf(fmaxf(tacc[2][0], tacc[2][1]), fmaxf(tacc[2][2], tacc[2][3])),
              fmaxf(fmaxf(tacc[3][0], tacc[3][1]), fmaxf(tacc[3][2], tacc[3][3]))));
    rm = fmaxf(rm, __shfl_xor(rm, 16, 64));
    rm = fmaxf(rm, __shfl_xor(rm, 32, 64));

    // THR=0 exact-skip: when skipped, the rescale would have been *1.0 exactly
    if (__any(rm > mrow)) {
      const float nm = fmaxf(mrow, rm);
      const float sc = exp2f((mrow - nm) * L2E);
      mrow = nm;
      lrow *= sc;
#pragma unroll
      for (int r = 0; r < 4; ++r) {
        const float so = __shfl(sc, 20 * lg + r, 64);
#pragma unroll
        for (int nt = 0; nt < 4; ++nt) o[nt][r] *= so;
      }
    }

    const float nmL = mrow * L2E;
    float p[4][4];
    float rs = 0.0f;
#pragma unroll
    for (int ks = 0; ks < 4; ++ks)
#pragma unroll
      for (int r = 0; r < 4; ++r) {
        const float pv = exp2f(fmaf(tacc[ks][r], L2E, -nmL));
        p[ks][r] = pv;
        rs += pv;
      }
    rs += __shfl_xor(rs, 16, 64);
    rs += __shfl_xor(rs, 32, 64);
    lrow += rs;

    // ---- P pack: 8x v_cvt_pk_bf16_f32 (shorts[0..3]=p[2s2], [4..7]=p[2s2+1]) ----
    short8_t pf[2];
#pragma unroll
    for (int s2 = 0; s2 < 2; ++s2) {
      u32x4_t pu;
      pu[0] = pkbf(p[2 * s2][0], p[2 * s2][1]);
      pu[1] = pkbf(p[2 * s2][2], p[2 * s2][3]);
      pu[2] = pkbf(p[2 * s2 + 1][0], p[2 * s2 + 1][1]);
      pu[3] = pkbf(p[2 * s2 + 1][2], p[2 * s2 + 1][3]);
      pf[s2] = __builtin_bit_cast(short8_t, pu);
    }

    asm volatile("s_waitcnt lgkmcnt(0)");
    __builtin_amdgcn_sched_barrier(0);

    __builtin_amdgcn_s_setprio(1);
#pragma unroll
    for (int nt = 0; nt < 4; ++nt) {
#pragma unroll
      for (int s2 = 0; s2 < 2; ++s2) {
        short8_t bv = __builtin_shufflevector(vf[nt][s2][0], vf[nt][s2][1],
                                              0, 1, 2, 3, 4, 5, 6, 7);
        o[nt] = __builtin_amdgcn_mfma_f32_16x16x32_bf16(pf[s2], bv, o[nt], 0, 0, 0);
      }
    }
    __builtin_amdgcn_s_setprio(0);
    cur ^= 1;
  }
#undef STAGE

  // ---- epilogue: normalize and write ctx ----
  const float linv = 1.0f / lrow;
#pragma unroll
  for (int r = 0; r < 4; ++r) {
    const float li = __shfl(linv, 20 * lg + r, 64);
    u16* op = ctx + (size_t)(b * S_LEN + qrow + 4 * lg + r) * EMB + h * HD;
#pragma unroll
    for (int nt = 0; nt < 4; ++nt)
      op[nt * 16 + ln15] = f2bf(o[nt][r] * li);
  }
}

// ---------------------------------------------------------------------------
extern "C" void kernel_launch(void* const* d_in, const int* in_sizes, int n_in,
                              void* d_out, int out_size, void* d_ws, size_t ws_size,
                              hipStream_t stream) {
  const float* x  = (const float*)d_in[0];
  const float* Wq = (const float*)d_in[1];
  const float* Wk = (const float*)d_in[2];
  const float* Wv = (const float*)d_in[3];
  const float* Wo = (const float*)d_in[4];
  const float* bo = (const float*)d_in[5];

  u16* ws   = (u16*)d_ws;
  u16* xb   = ws;                               // 4096*1024
  u16* wcat = xb + (size_t)MR * EMB;            // 3*1024*1024 (Wq|Wk|Wv rows)
  u16* wob  = wcat + (size_t)3 * EMB * EMB;     // 1024*1024
  u16* qkv  = wob + (size_t)EMB * EMB;          // 4096*3072
  u16* ctxb = qkv + (size_t)MR * E3;            // 4096*1024

  // fused fp32 -> bf16 (x | Wq*0.125 | Wk | Wv | Wo), dest contiguous at xb
  k_cvt_all<<<8192, 256, 0, stream>>>(x, Wq, Wk, Wv, Wo, xb);

  // QKV = x @ Wcat^T  (M=4096, N=3072, K=1024), bf16 out
  k_gemm_bt<false><<<dim3(E3 / 128, MR / 128), 256, 0, stream>>>(
      xb, wcat, qkv, nullptr, MR, E3, EMB);

  // causal flash attention -> ctx (bf16)
  k_attn2<<<dim3(BATCH * NH, 32), 256, 0, stream>>>(qkv, ctxb);

  // out = ctx @ Wo^T + bo  (fp32 out)
  k_gemm_bt<true><<<dim3(EMB / 128, MR / 128), 256, 0, stream>>>(
      ctxb, wob, d_out, bo, MR, EMB, EMB);
}